// Round 6
// baseline (347.135 us; speedup 1.0000x reference)
//
#include <hip/hip_runtime.h>

#define NG   2000
#define NPG  50
#define EPG  800
#define F0   64
#define FH   128
#define NN   51    // ODD stride: conflict-free for lane-along-node AND lane-along-feat
#define FP   512

// Column-split GEMM: HsT[16wv+j][lane] = sum_k XsT[k][lane] * W[k][16wv+j]
// lane = node (conflict-free b32 LDS); W loads wave-uniform -> s_load (SALU pipe).
// NOTE: lanes >= NPG must NOT store — HsT rows are only NN=51 wide (node dim!).
template<int K>
__device__ inline void gemm_body(const float (*__restrict__ XsT)[NN],
                                 float (*__restrict__ HsT)[NN],
                                 const float* __restrict__ W, int lane, int wv) {
    float acc[16];
#pragma unroll
    for (int j = 0; j < 16; ++j) acc[j] = 0.f;
    const float* Wp = W + wv * 16;
#pragma unroll 4
    for (int k = 0; k < K; ++k) {
        float a = XsT[k][lane];
        const float* wk = Wp + (size_t)k * FH;   // uniform -> scalar loads
#pragma unroll
        for (int j = 0; j < 16; ++j)
            acc[j] = fmaf(a, wk[j], acc[j]);
    }
    if (lane < NPG) {                 // exec-mask guard: no OOB row spill
#pragma unroll
        for (int j = 0; j < 16; ++j)
            HsT[wv * 16 + j][lane] = acc[j];
    }
}

__global__ __launch_bounds__(512, 6) void gcn_fused(
    const float* __restrict__ nf,
    const int*   __restrict__ pair,
    const int*   __restrict__ num_nodes,
    const float* __restrict__ W0, const float* __restrict__ b0,
    const float* __restrict__ W1, const float* __restrict__ b1,
    const float* __restrict__ W2, const float* __restrict__ b2,
    float* __restrict__ means)
{
    __shared__ float XsT[FH][NN];          // activations, feat-major [feat][node]
    __shared__ float HsT[FH][NN];          // GEMM out,    feat-major [feat][node]
    __shared__ unsigned int ssrc32[EPG/4]; // src ids bucketed by dst, byte-packed
    __shared__ int   degi[NPG], dego[NPG], pos[NPG];
    __shared__ float nin[NPG], nout[NPG];

    const int tid   = threadIdx.x;
    const int g     = blockIdx.x;
    const int base  = g * NPG;
    const int ebase = g * EPG;
    const int* srcp = pair;
    const int* dstp = pair + (size_t)NG * EPG;

    if (tid < NPG) { degi[tid] = 0; dego[tid] = 0; }
    __syncthreads();

    // ---- degrees ----
    for (int e = tid; e < EPG; e += 512) {
        int s = srcp[ebase + e] - base;
        int d = dstp[ebase + e] - base;
        atomicAdd(&dego[s], 1);
        atomicAdd(&degi[d], 1);
    }
    __syncthreads();

    // ---- norms + exclusive prefix scan of in-degrees (wave 0) ----
    if (tid < NPG) {
        nout[tid] = rsqrtf((float)max(dego[tid], 1));
        nin[tid]  = rsqrtf((float)max(degi[tid], 1));
    }
    if (tid < 64) {
        int v = (tid < NPG) ? degi[tid] : 0;
        int s = v;
#pragma unroll
        for (int o = 1; o < 64; o <<= 1) {
            int t = __shfl_up(s, o, 64);
            if (tid >= o) s += t;
        }
        if (tid < NPG) pos[tid] = s - v;   // start offsets; becomes end after fill
    }
    __syncthreads();

    // ---- bucket fill (byte writes; order within bucket arbitrary) ----
    {
        unsigned char* sb = (unsigned char*)ssrc32;
        for (int e = tid; e < EPG; e += 512) {
            int s = srcp[ebase + e] - base;
            int d = dstp[ebase + e] - base;
            int p = atomicAdd(&pos[d], 1);
            sb[p] = (unsigned char)s;
        }
    }
    // ---- load X0 transposed, scaled by norm_out ----
    for (int i = tid; i < NPG * (F0 / 4); i += 512) {
        int n = i >> 4, k4 = (i & 15) * 4;
        float4 v = *(const float4*)(nf + (size_t)(base + n) * F0 + k4);
        float sc = nout[n];
        XsT[k4 + 0][n] = v.x * sc;
        XsT[k4 + 1][n] = v.y * sc;
        XsT[k4 + 2][n] = v.z * sc;
        XsT[k4 + 3][n] = v.w * sc;
    }
    __syncthreads();

    const int lane = tid & 63;
    const int wv   = __builtin_amdgcn_readfirstlane(tid >> 6);  // wave id -> SGPR

    // XsT[f][d] = relu(sum_{s in N(d)} HsT[f][s] * nin[d] + b[f]) [* nout[d]]
    // f = tid&127 (lane-along-feat, conflict-free); 4 dst nodes per pass.
    auto aggregate = [&](const float* __restrict__ b, bool scale_out) {
        const int f  = tid & 127;
        const int dq = tid >> 7;           // 0..3, uniform per wave
        const float breg = b[f];
        for (int d0 = 0; d0 < NPG; d0 += 4) {
            int d = d0 + dq;
            if (d < NPG) {
                int end   = pos[d];        // end offset (post-fill)
                int cnt   = degi[d];
                int start = end - cnt;
                float acc = 0.f;
                for (int w = start >> 2; (w << 2) < end; ++w) {
                    unsigned int word = ssrc32[w];   // broadcast (uniform per d)
#pragma unroll
                    for (int j = 0; j < 4; ++j) {
                        int p = (w << 2) + j;
                        if (p >= start && p < end) { // uniform branch per wave
                            int s = (word >> (8 * j)) & 255;
                            acc += HsT[f][s];
                        }
                    }
                }
                float r = fmaxf(fmaf(acc, nin[d], breg), 0.f);
                if (scale_out) r *= nout[d];
                XsT[f][d] = r;
            }
        }
        __syncthreads();
    };

    gemm_body<F0>(XsT, HsT, W0, lane, wv);  __syncthreads();  aggregate(b0, true);
    gemm_body<FH>(XsT, HsT, W1, lane, wv);  __syncthreads();  aggregate(b1, true);
    gemm_body<FH>(XsT, HsT, W2, lane, wv);  __syncthreads();  aggregate(b2, false);

    // ---- mean pooling (pool buffer aliased onto dead HsT) ----
    {
        float* poolp = (float*)&HsT[0][0];
        int f = tid & 127, h = tid >> 7;
        float s = 0.f;
        for (int n = h; n < NPG; n += 4) s += XsT[f][n];
        poolp[h * FH + f] = s;
        __syncthreads();
        if (tid < FH) {
            float m = (poolp[tid] + poolp[FH + tid] + poolp[2 * FH + tid]
                       + poolp[3 * FH + tid]) / (float)num_nodes[g];
            means[(size_t)g * FH + tid] = m;
        }
    }
}

// ---------------- Kernel 2: MLP head ----------------
__global__ __launch_bounds__(512) void mlp_head(
    const float* __restrict__ means, const float* __restrict__ Wp1,
    const float* __restrict__ bp1,   const float* __restrict__ Wp2,
    const float* __restrict__ bp2,   float* __restrict__ out)
{
    __shared__ float ms[8][FH];
    __shared__ float wred[8][8];
    const int tid = threadIdx.x;
    const int g0  = blockIdx.x * 8;

    for (int i = tid; i < 8 * FH; i += 512)
        ms[i >> 7][i & 127] = means[(size_t)g0 * FH + i];
    __syncthreads();

    const int f = tid;
    float acc[8];
    float bb = bp1[f];
#pragma unroll
    for (int gi = 0; gi < 8; ++gi) acc[gi] = bb;
    for (int k = 0; k < FH; ++k) {
        float w = Wp1[(size_t)k * FP + f];
#pragma unroll
        for (int gi = 0; gi < 8; ++gi) acc[gi] += ms[gi][k] * w;
    }
    float w2 = Wp2[f];
#pragma unroll
    for (int gi = 0; gi < 8; ++gi) {
        float v = fmaxf(acc[gi], 0.f) * w2;
#pragma unroll
        for (int o = 32; o > 0; o >>= 1) v += __shfl_down(v, o, 64);
        if ((tid & 63) == 0) wred[tid >> 6][gi] = v;
    }
    __syncthreads();
    if (tid < 8) {
        float s = 0.f;
#pragma unroll
        for (int w = 0; w < 8; ++w) s += wred[w][tid];
        out[g0 + tid] = s + bp2[0];
    }
}

extern "C" void kernel_launch(void* const* d_in, const int* in_sizes, int n_in,
                              void* d_out, int out_size, void* d_ws, size_t ws_size,
                              hipStream_t stream) {
    const float* nf   = (const float*)d_in[0];
    const int*   pair = (const int*)d_in[2];
    const int*   nn   = (const int*)d_in[3];
    const float* W0  = (const float*)d_in[5];  const float* b0  = (const float*)d_in[6];
    const float* W1  = (const float*)d_in[7];  const float* b1  = (const float*)d_in[8];
    const float* W2  = (const float*)d_in[9];  const float* b2  = (const float*)d_in[10];
    const float* Wp1 = (const float*)d_in[11]; const float* bp1 = (const float*)d_in[12];
    const float* Wp2 = (const float*)d_in[13]; const float* bp2 = (const float*)d_in[14];

    float* means = (float*)d_ws;   // 2000*128*4 = 1 MB
    float* out   = (float*)d_out;

    hipLaunchKernelGGL(gcn_fused, dim3(NG), dim3(512), 0, stream,
                       nf, pair, nn, W0, b0, W1, b1, W2, b2, means);
    hipLaunchKernelGGL(mlp_head, dim3(NG / 8), dim3(512), 0, stream,
                       means, Wp1, bp1, Wp2, bp2, out);
}

// Round 7
// 190.754 us; speedup vs baseline: 1.8198x; 1.8198x over previous
//
#include <hip/hip_runtime.h>

#define NG   2000
#define NPG  50
#define EPG  800
#define F0   64
#define FH   128
#define NN   51     // XsT row stride (odd -> strided b32 writes ~conflict-free)
#define HS   132    // Hs row stride in floats (16B-aligned; bank-stride 4 -> 2-way b128 stores)
#define NW   240    // bucket words: sum ceil(deg/4)*4 <= 800 + 3*50 = 950 bytes
#define FP   512

// Column-split GEMM: Hs[lane][16wv+j] = sum_k XsT[k][lane] * W[k][16wv+j]
// lane = node; XsT reads row-contiguous b32 (2-way, free). W wave-uniform -> s_load.
template<int K>
__device__ inline void gemm_body(const float (*__restrict__ XsT)[NN],
                                 float (*__restrict__ Hs)[HS],
                                 const float* __restrict__ W, int lane, int wv) {
    float4 acc[4];
#pragma unroll
    for (int q = 0; q < 4; ++q) acc[q] = make_float4(0.f, 0.f, 0.f, 0.f);
    const float* Wp = W + wv * 16;
#pragma unroll 4
    for (int k = 0; k < K; ++k) {
        float a = XsT[k][lane];
        const float* wk = Wp + (size_t)k * FH;   // uniform address -> scalar loads
#pragma unroll
        for (int q = 0; q < 4; ++q) {
            acc[q].x = fmaf(a, wk[q * 4 + 0], acc[q].x);
            acc[q].y = fmaf(a, wk[q * 4 + 1], acc[q].y);
            acc[q].z = fmaf(a, wk[q * 4 + 2], acc[q].z);
            acc[q].w = fmaf(a, wk[q * 4 + 3], acc[q].w);
        }
    }
    if (lane < NPG) {                 // rows 50..63 never stored; row 50 stays zero
#pragma unroll
        for (int q = 0; q < 4; ++q)
            *(float4*)(&Hs[lane][wv * 16 + q * 4]) = acc[q];
    }
}

__global__ __launch_bounds__(512, 2) void gcn_fused(
    const float* __restrict__ nf,
    const int*   __restrict__ pair,
    const int*   __restrict__ num_nodes,
    const float* __restrict__ W0, const float* __restrict__ b0,
    const float* __restrict__ W1, const float* __restrict__ b1,
    const float* __restrict__ W2, const float* __restrict__ b2,
    float* __restrict__ means)
{
    __shared__ float XsT[FH][NN];          // GEMM input, feat-major [feat][node]
    __shared__ float Hs[NPG + 1][HS];      // GEMM output, node-major; row 50 = zero (dummy)
    __shared__ unsigned int ssrc32[NW];    // byte-packed buckets, padded with 50
    __shared__ int   degi[NPG], cur[NPG], off[NPG];
    __shared__ float nin[NPG], nout[NPG];

    const int tid   = threadIdx.x;
    const int g     = blockIdx.x;
    const int base  = g * NPG;
    const int ebase = g * EPG;
    const int* srcp = pair;
    const int* dstp = pair + (size_t)NG * EPG;

    if (tid < NPG) { degi[tid] = 0; cur[tid] = 0; }
    __syncthreads();

    // ---- degrees (cur = out-degree for now) ----
    for (int e = tid; e < EPG; e += 512) {
        int s = srcp[ebase + e] - base;
        int d = dstp[ebase + e] - base;
        atomicAdd(&cur[s], 1);
        atomicAdd(&degi[d], 1);
    }
    __syncthreads();

    // ---- norms; padded-count exclusive scan (wave 0); ssrc init; zero Hs row 50 ----
    if (tid < NPG) {
        nout[tid] = rsqrtf((float)max(cur[tid], 1));
        nin[tid]  = rsqrtf((float)max(degi[tid], 1));
    }
    if (tid < 64) {
        int v = (tid < NPG) ? ((degi[tid] + 3) & ~3) : 0;
        int s = v;
#pragma unroll
        for (int o = 1; o < 64; o <<= 1) {
            int t = __shfl_up(s, o, 64);
            if (tid >= o) s += t;
        }
        if (tid < NPG) off[tid] = s - v;
    }
    if (tid >= 64 && tid < 64 + NW) ssrc32[tid - 64] = 0x32323232u;  // byte 50 = dummy
    if (tid >= 320 && tid < 320 + 33)
        *(float4*)(&Hs[NPG][(tid - 320) * 4]) = make_float4(0.f, 0.f, 0.f, 0.f);
    __syncthreads();

    // ---- reset cur; load X0 transposed (scaled by norm_out) ----
    if (tid < NPG) cur[tid] = 0;
    for (int i = tid; i < NPG * (F0 / 4); i += 512) {
        int n = i >> 4, k4 = (i & 15) * 4;
        float4 v = *(const float4*)(nf + (size_t)(base + n) * F0 + k4);
        float sc = nout[n];
        XsT[k4 + 0][n] = v.x * sc;
        XsT[k4 + 1][n] = v.y * sc;
        XsT[k4 + 2][n] = v.z * sc;
        XsT[k4 + 3][n] = v.w * sc;
    }
    __syncthreads();

    // ---- bucket fill (unused padded slots keep dummy 50) ----
    {
        unsigned char* sb = (unsigned char*)ssrc32;
        for (int e = tid; e < EPG; e += 512) {
            int s = srcp[ebase + e] - base;
            int d = dstp[ebase + e] - base;
            int p = atomicAdd(&cur[d], 1);
            sb[off[d] + p] = (unsigned char)s;
        }
    }
    __syncthreads();

    const int lane = tid & 63;
    const int wv   = __builtin_amdgcn_readfirstlane(tid >> 6);  // wave id (SGPR)

    // Aggregate v3: one dst per wave; lanes 0-31 row A, lanes 32-63 row B,
    // all reads contiguous float4 (conflict-free). Dummies hit zero row 50.
    auto aggregate = [&](const float* __restrict__ b, bool scale_out) {
        const int half = lane >> 5;
        const int l32  = lane & 31;
        const float4 bb = *(const float4*)(b + l32 * 4);
        for (int d = wv; d < NPG; d += 8) {
            const int w0 = off[d] >> 2;
            const int nw = (degi[d] + 3) >> 2;
            float4 a0 = make_float4(0.f, 0.f, 0.f, 0.f), a1 = a0;
#pragma unroll 2
            for (int w = w0; w < w0 + nw; ++w) {
                unsigned int word = ssrc32[w];           // broadcast read
                int sA = (word >> (8 * half)) & 255;     // bytes 0 / 1
                int sB = (word >> (16 + 8 * half)) & 255;// bytes 2 / 3
                float4 hA = *(const float4*)(&Hs[sA][l32 * 4]);
                float4 hB = *(const float4*)(&Hs[sB][l32 * 4]);
                a0.x += hA.x; a0.y += hA.y; a0.z += hA.z; a0.w += hA.w;
                a1.x += hB.x; a1.y += hB.y; a1.z += hB.z; a1.w += hB.w;
            }
            a0.x += a1.x; a0.y += a1.y; a0.z += a1.z; a0.w += a1.w;
            a0.x += __shfl_xor(a0.x, 32, 64);
            a0.y += __shfl_xor(a0.y, 32, 64);
            a0.z += __shfl_xor(a0.z, 32, 64);
            a0.w += __shfl_xor(a0.w, 32, 64);
            if (half == 0) {
                float ni = nin[d];
                float4 r;
                r.x = fmaxf(fmaf(a0.x, ni, bb.x), 0.f);
                r.y = fmaxf(fmaf(a0.y, ni, bb.y), 0.f);
                r.z = fmaxf(fmaf(a0.z, ni, bb.z), 0.f);
                r.w = fmaxf(fmaf(a0.w, ni, bb.w), 0.f);
                if (scale_out) {
                    float no = nout[d];
                    r.x *= no; r.y *= no; r.z *= no; r.w *= no;
                }
                XsT[l32 * 4 + 0][d] = r.x;   // odd stride -> ~2-way writes
                XsT[l32 * 4 + 1][d] = r.y;
                XsT[l32 * 4 + 2][d] = r.z;
                XsT[l32 * 4 + 3][d] = r.w;
            }
        }
        __syncthreads();
    };

    gemm_body<F0>(XsT, Hs, W0, lane, wv);  __syncthreads();  aggregate(b0, true);
    gemm_body<FH>(XsT, Hs, W1, lane, wv);  __syncthreads();  aggregate(b1, true);
    gemm_body<FH>(XsT, Hs, W2, lane, wv);  __syncthreads();  aggregate(b2, false);

    // ---- mean pooling (scratch aliased onto dead Hs) ----
    {
        float* poolp = (float*)&Hs[0][0];
        int f = tid & 127, h = tid >> 7;
        float s = 0.f;
        for (int n = h; n < NPG; n += 4) s += XsT[f][n];
        __syncthreads();               // Hs reads (aggregate) done before overwrite
        poolp[h * FH + f] = s;
        __syncthreads();
        if (tid < FH) {
            float m = (poolp[tid] + poolp[FH + tid] + poolp[2 * FH + tid]
                       + poolp[3 * FH + tid]) / (float)num_nodes[g];
            means[(size_t)g * FH + tid] = m;
        }
    }
}

// ---------------- Kernel 2: MLP head ----------------
__global__ __launch_bounds__(512) void mlp_head(
    const float* __restrict__ means, const float* __restrict__ Wp1,
    const float* __restrict__ bp1,   const float* __restrict__ Wp2,
    const float* __restrict__ bp2,   float* __restrict__ out)
{
    __shared__ float ms[8][FH];
    __shared__ float wred[8][8];
    const int tid = threadIdx.x;
    const int g0  = blockIdx.x * 8;

    for (int i = tid; i < 8 * FH; i += 512)
        ms[i >> 7][i & 127] = means[(size_t)g0 * FH + i];
    __syncthreads();

    const int f = tid;
    float acc[8];
    float bb = bp1[f];
#pragma unroll
    for (int gi = 0; gi < 8; ++gi) acc[gi] = bb;
    for (int k = 0; k < FH; ++k) {
        float w = Wp1[(size_t)k * FP + f];
#pragma unroll
        for (int gi = 0; gi < 8; ++gi) acc[gi] += ms[gi][k] * w;
    }
    float w2 = Wp2[f];
#pragma unroll
    for (int gi = 0; gi < 8; ++gi) {
        float v = fmaxf(acc[gi], 0.f) * w2;
#pragma unroll
        for (int o = 32; o > 0; o >>= 1) v += __shfl_down(v, o, 64);
        if ((tid & 63) == 0) wred[tid >> 6][gi] = v;
    }
    __syncthreads();
    if (tid < 8) {
        float s = 0.f;
#pragma unroll
        for (int w = 0; w < 8; ++w) s += wred[w][tid];
        out[g0 + tid] = s + bp2[0];
    }
}

extern "C" void kernel_launch(void* const* d_in, const int* in_sizes, int n_in,
                              void* d_out, int out_size, void* d_ws, size_t ws_size,
                              hipStream_t stream) {
    const float* nf   = (const float*)d_in[0];
    const int*   pair = (const int*)d_in[2];
    const int*   nn   = (const int*)d_in[3];
    const float* W0  = (const float*)d_in[5];  const float* b0  = (const float*)d_in[6];
    const float* W1  = (const float*)d_in[7];  const float* b1  = (const float*)d_in[8];
    const float* W2  = (const float*)d_in[9];  const float* b2  = (const float*)d_in[10];
    const float* Wp1 = (const float*)d_in[11]; const float* bp1 = (const float*)d_in[12];
    const float* Wp2 = (const float*)d_in[13]; const float* bp2 = (const float*)d_in[14];

    float* means = (float*)d_ws;   // 2000*128*4 = 1 MB
    float* out   = (float*)d_out;

    hipLaunchKernelGGL(gcn_fused, dim3(NG), dim3(512), 0, stream,
                       nf, pair, nn, W0, b0, W1, b1, W2, b2, means);
    hipLaunchKernelGGL(mlp_head, dim3(NG / 8), dim3(512), 0, stream,
                       means, Wp1, bp1, Wp2, bp2, out);
}

// Round 8
// 109.764 us; speedup vs baseline: 3.1626x; 1.7379x over previous
//
#include <hip/hip_runtime.h>

#define NG   2000
#define NPG  50
#define EPG  800
#define F0   64
#define FH   128
#define FP   512

typedef __attribute__((ext_vector_type(8))) short  short8;
typedef __attribute__((ext_vector_type(8))) __bf16 bf16x8;
typedef __attribute__((ext_vector_type(4))) float  f32x4;
typedef unsigned short u16;
typedef unsigned int   u32;

__device__ inline u16 bf16_rne(float x) {
    u32 u = __builtin_bit_cast(u32, x);
    u += 0x7fffu + ((u >> 16) & 1u);
    return (u16)(u >> 16);
}
__device__ inline float bf16f(u16 h) {
    u32 u = ((u32)h) << 16;
    return __builtin_bit_cast(float, u);
}
__device__ inline f32x4 mfma16(short8 a, short8 b, f32x4 c) {
    return __builtin_amdgcn_mfma_f32_16x16x32_bf16(
        __builtin_bit_cast(bf16x8, a), __builtin_bit_cast(bf16x8, b), c, 0, 0, 0);
}

// Swizzled LDS index helpers (XOR row-bits into 16B-chunk bits -> <=2-way banks)
__device__ inline int xb_idx(int row, int col)  { return row * 128 + (col  ^ ((row  & 7) << 3)); } // u16 units
__device__ inline int tb_idx(int feat, int node){ return feat * 64 + (node ^ ((feat & 7) << 3)); } // u16 units
__device__ inline int ah_idx(int d, int s)      { return d * 64 + (s ^ ((d & 7) << 2)); }          // f32 units

// ---------- one-time W split+pack into MFMA B-fragment layout ----------
// frag id: L0: nsub*2+kstep (16) | L1: 16+nsub*4+kstep (32) | L2: 48+... (32)
// value at (fid, lane, i) = W[kstep*32 + (lane>>4)*8 + i][nsub*16 + (lane&15)]
__global__ __launch_bounds__(256) void pack_w(
    const float* __restrict__ W0, const float* __restrict__ W1,
    const float* __restrict__ W2, u16* __restrict__ WpH, u16* __restrict__ WpL)
{
    int t = blockIdx.x * 256 + threadIdx.x;
    if (t >= 80 * 64) return;
    int fid = t >> 6, lane = t & 63;
    const float* W; int nsub, kstep;
    if (fid < 16)      { W = W0; int r = fid;      nsub = r >> 1; kstep = r & 1; }
    else if (fid < 48) { W = W1; int r = fid - 16; nsub = r >> 2; kstep = r & 3; }
    else               { W = W2; int r = fid - 48; nsub = r >> 2; kstep = r & 3; }
    int n  = nsub * 16 + (lane & 15);
    int kb = kstep * 32 + (lane >> 4) * 8;
    size_t off = (size_t)fid * 512 + (size_t)lane * 8;
#pragma unroll
    for (int i = 0; i < 8; ++i) {
        float v = W[(size_t)(kb + i) * FH + n];
        u16 h = bf16_rne(v);
        WpH[off + i] = h;
        WpL[off + i] = bf16_rne(v - bf16f(h));
    }
}

// ---------- per-wave MFMA pieces ----------
// MFMA1: T^T[feat][node] = (X @ W)^T  (A = X from LDS hi/lo, B = packed W from global)
template<int KST>
__device__ void mfma1_fn(const u16* __restrict__ WpH, const u16* __restrict__ WpL,
                         int fid0, const u16* XbH, const u16* XbL,
                         u16* TbH, u16* TbL, int lane, int mstrip, int nhalf)
{
    const int l15 = lane & 15, lk = lane >> 4;
    const int arow = mstrip * 16 + l15;
    short8 ah[KST], al[KST];
#pragma unroll
    for (int ks = 0; ks < KST; ++ks) {
        int c0 = ks * 32 + lk * 8;
        ah[ks] = *(const short8*)&XbH[xb_idx(arow, c0)];
        al[ks] = *(const short8*)&XbL[xb_idx(arow, c0)];
    }
#pragma unroll
    for (int ns = 0; ns < 4; ++ns) {
        int nsg = nhalf * 4 + ns;
        f32x4 acc = {0.f, 0.f, 0.f, 0.f};
#pragma unroll
        for (int ks = 0; ks < KST; ++ks) {
            size_t off = ((size_t)(fid0 + nsg * KST + ks)) * 512 + (size_t)lane * 8;
            short8 bh = *(const short8*)(WpH + off);
            short8 bl = *(const short8*)(WpL + off);
            acc = mfma16(ah[ks], bh, acc);   // hi*hi
            acc = mfma16(ah[ks], bl, acc);   // hi*lo
            acc = mfma16(al[ks], bh, acc);   // lo*hi
        }
        int feat = nsg * 16 + l15;
        int nb   = mstrip * 16 + lk * 4;     // D rows = nodes (consecutive 4)
#pragma unroll
        for (int rp = 0; rp < 2; ++rp) {     // pack row pairs -> u32 writes
            float v0 = acc[rp * 2], v1 = acc[rp * 2 + 1];
            u16 h0 = bf16_rne(v0), h1 = bf16_rne(v1);
            u16 q0 = bf16_rne(v0 - bf16f(h0)), q1 = bf16_rne(v1 - bf16f(h1));
            int idx = tb_idx(feat, nb + rp * 2);
            *(u32*)&TbH[idx] = (u32)h0 | ((u32)h1 << 16);
            *(u32*)&TbL[idx] = (u32)q0 | ((u32)q1 << 16);
        }
    }
}

// MFMA2: X' = relu(Ahat @ T + b)  (A = Ahat fp32->split on the fly, B = T^T)
template<bool LAST>
__device__ void mfma2_fn(const float* __restrict__ bias, const float* Ahat,
                         const u16* TbH, const u16* TbL,
                         u16* XbH, u16* XbL, float* pool,
                         int lane, int mstrip, int nhalf)
{
    const int l15 = lane & 15, lk = lane >> 4;
    const int arow = mstrip * 16 + l15;
    short8 ah[2], al[2];
#pragma unroll
    for (int ks = 0; ks < 2; ++ks) {
        float av[8];
        if (arow < NPG) {
            int s0 = ks * 32 + lk * 8;
            float4 p0 = *(const float4*)&Ahat[ah_idx(arow, s0)];
            float4 p1 = *(const float4*)&Ahat[ah_idx(arow, s0 + 4)];
            av[0] = p0.x; av[1] = p0.y; av[2] = p0.z; av[3] = p0.w;
            av[4] = p1.x; av[5] = p1.y; av[6] = p1.z; av[7] = p1.w;
        } else {
#pragma unroll
            for (int i = 0; i < 8; ++i) av[i] = 0.f;   // pad rows 50-63 = 0
        }
        short8 a_h, a_l;
#pragma unroll
        for (int i = 0; i < 8; ++i) {
            u16 h = bf16_rne(av[i]);
            a_h[i] = (short)h;
            a_l[i] = (short)bf16_rne(av[i] - bf16f(h));
        }
        ah[ks] = a_h; al[ks] = a_l;
    }
#pragma unroll
    for (int ns = 0; ns < 4; ++ns) {
        int nsg  = nhalf * 4 + ns;
        int feat = nsg * 16 + l15;
        float bc = bias[feat];
        f32x4 acc = {0.f, 0.f, 0.f, 0.f};
#pragma unroll
        for (int ks = 0; ks < 2; ++ks) {
            short8 bh = *(const short8*)&TbH[tb_idx(feat, ks * 32 + lk * 8)];
            short8 bl = *(const short8*)&TbL[tb_idx(feat, ks * 32 + lk * 8)];
            acc = mfma16(ah[ks], bh, acc);
            acc = mfma16(ah[ks], bl, acc);
            acc = mfma16(al[ks], bh, acc);
        }
        int nb = mstrip * 16 + lk * 4;
        float vs = 0.f;
#pragma unroll
        for (int r = 0; r < 4; ++r) {
            int row = nb + r;
            float v = fmaxf(acc[r] + bc, 0.f);
            if (row >= NPG) v = 0.f;           // pad rows stay exactly zero
            if (LAST) {
                vs += v;
            } else {
                u16 h = bf16_rne(v);
                XbH[xb_idx(row, feat)] = h;
                XbL[xb_idx(row, feat)] = bf16_rne(v - bf16f(h));
            }
        }
        if (LAST) {
            vs += __shfl_xor(vs, 16, 64);      // reduce over lane>>4 row groups
            vs += __shfl_xor(vs, 32, 64);
            if (lane < 16) atomicAdd(&pool[nsg * 16 + lane], vs);
        }
    }
}

// ---------- main fused kernel: one block = one graph ----------
__global__ __launch_bounds__(512, 2) void gcn_fused(
    const float* __restrict__ nf, const int* __restrict__ pair,
    const int* __restrict__ num_nodes,
    const float* __restrict__ b0, const float* __restrict__ b1,
    const float* __restrict__ b2,
    const u16* __restrict__ WpH, const u16* __restrict__ WpL,
    float* __restrict__ means)
{
    __shared__ u16 XbH[64 * 128], XbL[64 * 128];   // X hi/lo, [node][feat], swizzled
    __shared__ u16 TbH[128 * 64], TbL[128 * 64];   // T^T hi/lo, [feat][node], swizzled
    __shared__ float Ahat[NPG * 64];               // dense normalized adjacency
    __shared__ float pool[FH];
    __shared__ int   din[NPG], dout[NPG];
    __shared__ float nin[NPG], nout[NPG];

    const int tid  = threadIdx.x;
    const int g    = blockIdx.x;
    const int base = g * NPG, ebase = g * EPG;
    const int* srcp = pair;
    const int* dstp = pair + (size_t)NG * EPG;

    // ---- init ----
    if (tid < NPG) { din[tid] = 0; dout[tid] = 0; }
    for (int i = tid; i < NPG * 64; i += 512) Ahat[i] = 0.f;
    if (tid < FH) pool[tid] = 0.f;
    for (int i = 3200 + tid; i < 4096; i += 512) {  // Xb rows 50-63, all cols
        ((u32*)XbH)[i] = 0u; ((u32*)XbL)[i] = 0u;
    }
    __syncthreads();

    // ---- degrees ----
    for (int e = tid; e < EPG; e += 512) {
        atomicAdd(&dout[srcp[ebase + e] - base], 1);
        atomicAdd(&din [dstp[ebase + e] - base], 1);
    }
    __syncthreads();
    if (tid < NPG) {
        nout[tid] = rsqrtf((float)max(dout[tid], 1));
        nin [tid] = rsqrtf((float)max(din [tid], 1));
    }
    __syncthreads();

    // ---- dense Ahat[d][s] += nin[d]*nout[s] per edge (multiplicity handled) ----
    for (int e = tid; e < EPG; e += 512) {
        int s = srcp[ebase + e] - base, d = dstp[ebase + e] - base;
        atomicAdd(&Ahat[ah_idx(d, s)], nin[d] * nout[s]);
    }
    // ---- X0 load + hi/lo split (no pre-scaling; norms live in Ahat) ----
    for (int i = tid; i < NPG * 16; i += 512) {
        int n = i >> 4, c4 = (i & 15) * 4;
        float4 v = *(const float4*)(nf + (size_t)(base + n) * F0 + c4);
        u16 h0 = bf16_rne(v.x), h1 = bf16_rne(v.y), h2 = bf16_rne(v.z), h3 = bf16_rne(v.w);
        int idx = xb_idx(n, c4);
        *(u32*)&XbH[idx]     = (u32)h0 | ((u32)h1 << 16);
        *(u32*)&XbH[idx + 2] = (u32)h2 | ((u32)h3 << 16);
        u16 l0 = bf16_rne(v.x - bf16f(h0)), l1 = bf16_rne(v.y - bf16f(h1));
        u16 l2 = bf16_rne(v.z - bf16f(h2)), l3 = bf16_rne(v.w - bf16f(h3));
        *(u32*)&XbL[idx]     = (u32)l0 | ((u32)l1 << 16);
        *(u32*)&XbL[idx + 2] = (u32)l2 | ((u32)l3 << 16);
    }
    __syncthreads();

    const int lane   = tid & 63;
    const int wv     = __builtin_amdgcn_readfirstlane(tid >> 6);
    const int mstrip = wv & 3, nhalf = wv >> 2;

    mfma1_fn<2>(WpH, WpL, 0,  XbH, XbL, TbH, TbL, lane, mstrip, nhalf);
    __syncthreads();
    mfma2_fn<false>(b0, Ahat, TbH, TbL, XbH, XbL, pool, lane, mstrip, nhalf);
    __syncthreads();
    mfma1_fn<4>(WpH, WpL, 16, XbH, XbL, TbH, TbL, lane, mstrip, nhalf);
    __syncthreads();
    mfma2_fn<false>(b1, Ahat, TbH, TbL, XbH, XbL, pool, lane, mstrip, nhalf);
    __syncthreads();
    mfma1_fn<4>(WpH, WpL, 48, XbH, XbL, TbH, TbL, lane, mstrip, nhalf);
    __syncthreads();
    mfma2_fn<true>(b2, Ahat, TbH, TbL, XbH, XbL, pool, lane, mstrip, nhalf);
    __syncthreads();

    if (tid < FH) means[(size_t)g * FH + tid] = pool[tid] / (float)num_nodes[g];
}

// ---------------- Kernel 3: MLP head (unchanged) ----------------
__global__ __launch_bounds__(512) void mlp_head(
    const float* __restrict__ means, const float* __restrict__ Wp1,
    const float* __restrict__ bp1,   const float* __restrict__ Wp2,
    const float* __restrict__ bp2,   float* __restrict__ out)
{
    __shared__ float ms[8][FH];
    __shared__ float wred[8][8];
    const int tid = threadIdx.x;
    const int g0  = blockIdx.x * 8;

    for (int i = tid; i < 8 * FH; i += 512)
        ms[i >> 7][i & 127] = means[(size_t)g0 * FH + i];
    __syncthreads();

    const int f = tid;
    float acc[8];
    float bb = bp1[f];
#pragma unroll
    for (int gi = 0; gi < 8; ++gi) acc[gi] = bb;
    for (int k = 0; k < FH; ++k) {
        float w = Wp1[(size_t)k * FP + f];
#pragma unroll
        for (int gi = 0; gi < 8; ++gi) acc[gi] += ms[gi][k] * w;
    }
    float w2 = Wp2[f];
#pragma unroll
    for (int gi = 0; gi < 8; ++gi) {
        float v = fmaxf(acc[gi], 0.f) * w2;
#pragma unroll
        for (int o = 32; o > 0; o >>= 1) v += __shfl_down(v, o, 64);
        if ((tid & 63) == 0) wred[tid >> 6][gi] = v;
    }
    __syncthreads();
    if (tid < 8) {
        float s = 0.f;
#pragma unroll
        for (int w = 0; w < 8; ++w) s += wred[w][tid];
        out[g0 + tid] = s + bp2[0];
    }
}

extern "C" void kernel_launch(void* const* d_in, const int* in_sizes, int n_in,
                              void* d_out, int out_size, void* d_ws, size_t ws_size,
                              hipStream_t stream) {
    const float* nf   = (const float*)d_in[0];
    const int*   pair = (const int*)d_in[2];
    const int*   nn   = (const int*)d_in[3];
    const float* W0  = (const float*)d_in[5];  const float* b0  = (const float*)d_in[6];
    const float* W1  = (const float*)d_in[7];  const float* b1  = (const float*)d_in[8];
    const float* W2  = (const float*)d_in[9];  const float* b2  = (const float*)d_in[10];
    const float* Wp1 = (const float*)d_in[11]; const float* bp1 = (const float*)d_in[12];
    const float* Wp2 = (const float*)d_in[13]; const float* bp2 = (const float*)d_in[14];

    float* means = (float*)d_ws;                                   // 1,024,000 B
    u16*   WpH   = (u16*)((char*)d_ws + (1 << 20));                // 81,920 B
    u16*   WpL   = (u16*)((char*)d_ws + (1 << 20) + 80 * 1024);    // 81,920 B
    float* out   = (float*)d_out;

    hipLaunchKernelGGL(pack_w, dim3(20), dim3(256), 0, stream, W0, W1, W2, WpH, WpL);
    hipLaunchKernelGGL(gcn_fused, dim3(NG), dim3(512), 0, stream,
                       nf, pair, nn, b0, b1, b2, WpH, WpL, means);
    hipLaunchKernelGGL(mlp_head, dim3(NG / 8), dim3(512), 0, stream,
                       means, Wp1, bp1, Wp2, bp2, out);
}

// Round 9
// 101.488 us; speedup vs baseline: 3.4204x; 1.0815x over previous
//
#include <hip/hip_runtime.h>

#define NG   2000
#define NPG  50
#define EPG  800
#define F0   64
#define FH   128
#define FP   512

typedef __attribute__((ext_vector_type(8))) short  short8;
typedef __attribute__((ext_vector_type(8))) __bf16 bf16x8;
typedef __attribute__((ext_vector_type(4))) float  f32x4;
typedef unsigned short u16;
typedef unsigned int   u32;

__device__ inline u16 bf16_rne(float x) {
    u32 u = __builtin_bit_cast(u32, x);
    u += 0x7fffu + ((u >> 16) & 1u);
    return (u16)(u >> 16);
}
__device__ inline float bf16f(u16 h) {
    u32 u = ((u32)h) << 16;
    return __builtin_bit_cast(float, u);
}
__device__ inline f32x4 mfma16(short8 a, short8 b, f32x4 c) {
    return __builtin_amdgcn_mfma_f32_16x16x32_bf16(
        __builtin_bit_cast(bf16x8, a), __builtin_bit_cast(bf16x8, b), c, 0, 0, 0);
}

// Swizzled LDS index helpers (XOR row-bits into 16B-chunk bits -> <=2-way banks)
__device__ inline int xb_idx(int row, int col)  { return row * 128 + (col  ^ ((row  & 7) << 3)); } // u16 units
__device__ inline int tb_idx(int feat, int node){ return feat * 64 + (node ^ ((feat & 7) << 3)); } // u16 units
__device__ inline int ah_idx(int d, int s)      { return d * 64 + (s ^ ((d & 7) << 2)); }          // u32/f32 units

// ---------- one-time W split+pack into MFMA B-fragment layout ----------
__global__ __launch_bounds__(256) void pack_w(
    const float* __restrict__ W0, const float* __restrict__ W1,
    const float* __restrict__ W2, u16* __restrict__ WpH, u16* __restrict__ WpL)
{
    int t = blockIdx.x * 256 + threadIdx.x;
    if (t >= 80 * 64) return;
    int fid = t >> 6, lane = t & 63;
    const float* W; int nsub, kstep;
    if (fid < 16)      { W = W0; int r = fid;      nsub = r >> 1; kstep = r & 1; }
    else if (fid < 48) { W = W1; int r = fid - 16; nsub = r >> 2; kstep = r & 3; }
    else               { W = W2; int r = fid - 48; nsub = r >> 2; kstep = r & 3; }
    int n  = nsub * 16 + (lane & 15);
    int kb = kstep * 32 + (lane >> 4) * 8;
    size_t off = (size_t)fid * 512 + (size_t)lane * 8;
#pragma unroll
    for (int i = 0; i < 8; ++i) {
        float v = W[(size_t)(kb + i) * FH + n];
        u16 h = bf16_rne(v);
        WpH[off + i] = h;
        WpL[off + i] = bf16_rne(v - bf16f(h));
    }
}

// ---------- MFMA1: T^T = (X @ W)^T ----------
template<int KST>
__device__ void mfma1_fn(const u16* __restrict__ WpH, const u16* __restrict__ WpL,
                         int fid0, const u16* XbH, const u16* XbL,
                         u16* TbH, u16* TbL, int lane, int mstrip, int nhalf)
{
    const int l15 = lane & 15, lk = lane >> 4;
    const int arow = mstrip * 16 + l15;
    short8 ah[KST], al[KST];
#pragma unroll
    for (int ks = 0; ks < KST; ++ks) {
        int c0 = ks * 32 + lk * 8;
        ah[ks] = *(const short8*)&XbH[xb_idx(arow, c0)];
        al[ks] = *(const short8*)&XbL[xb_idx(arow, c0)];
    }
#pragma unroll
    for (int ns = 0; ns < 4; ++ns) {
        int nsg = nhalf * 4 + ns;
        f32x4 acc = {0.f, 0.f, 0.f, 0.f};
#pragma unroll
        for (int ks = 0; ks < KST; ++ks) {
            size_t off = ((size_t)(fid0 + nsg * KST + ks)) * 512 + (size_t)lane * 8;
            short8 bh = *(const short8*)(WpH + off);
            short8 bl = *(const short8*)(WpL + off);
            acc = mfma16(ah[ks], bh, acc);
            acc = mfma16(ah[ks], bl, acc);
            acc = mfma16(al[ks], bh, acc);
        }
        int feat = nsg * 16 + l15;
        int nb   = mstrip * 16 + lk * 4;
#pragma unroll
        for (int rp = 0; rp < 2; ++rp) {
            float v0 = acc[rp * 2], v1 = acc[rp * 2 + 1];
            u16 h0 = bf16_rne(v0), h1 = bf16_rne(v1);
            u16 q0 = bf16_rne(v0 - bf16f(h0)), q1 = bf16_rne(v1 - bf16f(h1));
            int idx = tb_idx(feat, nb + rp * 2);
            *(u32*)&TbH[idx] = (u32)h0 | ((u32)h1 << 16);
            *(u32*)&TbL[idx] = (u32)q0 | ((u32)q1 << 16);
        }
    }
}

// ---------- MFMA2: X' = relu(Ahat @ T + b) ; Ahat pre-packed (hi|lo<<16) ----------
template<bool LAST>
__device__ void mfma2_fn(const float* __restrict__ bias, const u32* __restrict__ Apk,
                         const u16* TbH, const u16* TbL,
                         u16* XbH, u16* XbL, float* pool,
                         int lane, int mstrip, int nhalf)
{
    const int l15 = lane & 15, lk = lane >> 4;
    const int arow = mstrip * 16 + l15;
    const bool valid = (arow < NPG);
    const int rr = valid ? arow : 0;
    short8 ah[2], al[2];
#pragma unroll
    for (int ks = 0; ks < 2; ++ks) {
        int s0 = ks * 32 + lk * 8;
        uint4 qa = *(const uint4*)&Apk[ah_idx(rr, s0)];
        uint4 qb = *(const uint4*)&Apk[ah_idx(rr, s0 + 4)];
        if (!valid) { qa.x = qa.y = qa.z = qa.w = 0u; qb = qa; }
        u32 qs[8] = {qa.x, qa.y, qa.z, qa.w, qb.x, qb.y, qb.z, qb.w};
        short8 a_h, a_l;
#pragma unroll
        for (int i = 0; i < 8; ++i) {
            a_h[i] = (short)(qs[i] & 0xffffu);
            a_l[i] = (short)(qs[i] >> 16);
        }
        ah[ks] = a_h; al[ks] = a_l;
    }
#pragma unroll
    for (int ns = 0; ns < 4; ++ns) {
        int nsg  = nhalf * 4 + ns;
        int feat = nsg * 16 + l15;
        float bc = bias[feat];
        f32x4 acc = {0.f, 0.f, 0.f, 0.f};
#pragma unroll
        for (int ks = 0; ks < 2; ++ks) {
            short8 bh = *(const short8*)&TbH[tb_idx(feat, ks * 32 + lk * 8)];
            short8 bl = *(const short8*)&TbL[tb_idx(feat, ks * 32 + lk * 8)];
            acc = mfma16(ah[ks], bh, acc);
            acc = mfma16(ah[ks], bl, acc);
            acc = mfma16(al[ks], bh, acc);
        }
        int nb = mstrip * 16 + lk * 4;
        float vs = 0.f;
#pragma unroll
        for (int r = 0; r < 4; ++r) {
            int row = nb + r;
            float v = fmaxf(acc[r] + bc, 0.f);
            if (row >= NPG) v = 0.f;
            if (LAST) {
                vs += v;
            } else {
                u16 h = bf16_rne(v);
                XbH[xb_idx(row, feat)] = h;
                XbL[xb_idx(row, feat)] = bf16_rne(v - bf16f(h));
            }
        }
        if (LAST) {
            vs += __shfl_xor(vs, 16, 64);
            vs += __shfl_xor(vs, 32, 64);
            if (lane < 16) atomicAdd(&pool[nsg * 16 + lane], vs);
        }
    }
}

// ---------- main fused kernel: one block = one graph ----------
__global__ __launch_bounds__(512, 4) void gcn_fused(
    const float* __restrict__ nf, const int* __restrict__ pair,
    const int* __restrict__ num_nodes,
    const float* __restrict__ b0, const float* __restrict__ b1,
    const float* __restrict__ b2,
    const u16* __restrict__ WpH, const u16* __restrict__ WpL,
    float* __restrict__ means)
{
    __shared__ u16 XbH[64 * 128], XbL[64 * 128];   // X hi/lo, [node][feat], swizzled
    __shared__ u16 TbH[128 * 64], TbL[128 * 64];   // T^T hi/lo, [feat][node], swizzled
    __shared__ float Ahat[NPG * 64];               // count matrix -> packed bf16 pair (u32)
    __shared__ float pool[FH];
    __shared__ int   din[NPG], dout[NPG];
    __shared__ float nin[NPG], nout[NPG];

    const int tid  = threadIdx.x;
    const int g    = blockIdx.x;
    const int base = g * NPG, ebase = g * EPG;
    const int* srcp = pair;
    const int* dstp = pair + (size_t)NG * EPG;

    // ---- init ----
    if (tid < NPG) { din[tid] = 0; dout[tid] = 0; }
    for (int i = tid; i < NPG * 64; i += 512) Ahat[i] = 0.f;
    if (tid < FH) pool[tid] = 0.f;
    for (int i = 3200 + tid; i < 4096; i += 512) {  // Xb rows 50-63
        ((u32*)XbH)[i] = 0u; ((u32*)XbL)[i] = 0u;
    }
    __syncthreads();

    // ---- single edge pass: degrees + dense count matrix (exact int counts in f32) ----
    for (int e = tid; e < EPG; e += 512) {
        int s = srcp[ebase + e] - base, d = dstp[ebase + e] - base;
        atomicAdd(&dout[s], 1);
        atomicAdd(&din [d], 1);
        atomicAdd(&Ahat[ah_idx(d, s)], 1.0f);
    }
    // ---- X0 load + hi/lo split ----
    for (int i = tid; i < NPG * 16; i += 512) {
        int n = i >> 4, c4 = (i & 15) * 4;
        float4 v = *(const float4*)(nf + (size_t)(base + n) * F0 + c4);
        u16 h0 = bf16_rne(v.x), h1 = bf16_rne(v.y), h2 = bf16_rne(v.z), h3 = bf16_rne(v.w);
        int idx = xb_idx(n, c4);
        *(u32*)&XbH[idx]     = (u32)h0 | ((u32)h1 << 16);
        *(u32*)&XbH[idx + 2] = (u32)h2 | ((u32)h3 << 16);
        u16 l0 = bf16_rne(v.x - bf16f(h0)), l1 = bf16_rne(v.y - bf16f(h1));
        u16 l2 = bf16_rne(v.z - bf16f(h2)), l3 = bf16_rne(v.w - bf16f(h3));
        *(u32*)&XbL[idx]     = (u32)l0 | ((u32)l1 << 16);
        *(u32*)&XbL[idx + 2] = (u32)l2 | ((u32)l3 << 16);
    }
    __syncthreads();

    // ---- norms ----
    if (tid < NPG) {
        nout[tid] = rsqrtf((float)max(dout[tid], 1));
        nin [tid] = rsqrtf((float)max(din [tid], 1));
    }
    __syncthreads();

    const int lane   = tid & 63;
    const int wv     = __builtin_amdgcn_readfirstlane(tid >> 6);
    const int mstrip = wv & 3, nhalf = wv >> 2;

    // ---- scale + split Ahat in place (u32 = hi | lo<<16), fused with mfma1 L0 ----
    for (int i = tid; i < NPG * 64; i += 512) {
        int d = i >> 6, sp = i & 63;
        int s = sp ^ ((d & 7) << 2);            // logical col (involution)
        float sc = (s < NPG) ? nin[d] * nout[s] : 0.f;
        float v = Ahat[i] * sc;
        u16 h = bf16_rne(v);
        u16 l = bf16_rne(v - bf16f(h));
        ((u32*)Ahat)[i] = (u32)h | ((u32)l << 16);
    }
    mfma1_fn<2>(WpH, WpL, 0, XbH, XbL, TbH, TbL, lane, mstrip, nhalf);
    __syncthreads();

    const u32* Apk = (const u32*)Ahat;
    mfma2_fn<false>(b0, Apk, TbH, TbL, XbH, XbL, pool, lane, mstrip, nhalf);
    __syncthreads();
    mfma1_fn<4>(WpH, WpL, 16, XbH, XbL, TbH, TbL, lane, mstrip, nhalf);
    __syncthreads();
    mfma2_fn<false>(b1, Apk, TbH, TbL, XbH, XbL, pool, lane, mstrip, nhalf);
    __syncthreads();
    mfma1_fn<4>(WpH, WpL, 48, XbH, XbL, TbH, TbL, lane, mstrip, nhalf);
    __syncthreads();
    mfma2_fn<true>(b2, Apk, TbH, TbL, XbH, XbL, pool, lane, mstrip, nhalf);
    __syncthreads();

    if (tid < FH) means[(size_t)g * FH + tid] = pool[tid] / (float)num_nodes[g];
}

// ---------------- Kernel 3: MLP head ----------------
__global__ __launch_bounds__(512) void mlp_head(
    const float* __restrict__ means, const float* __restrict__ Wp1,
    const float* __restrict__ bp1,   const float* __restrict__ Wp2,
    const float* __restrict__ bp2,   float* __restrict__ out)
{
    __shared__ float ms[8][FH];
    __shared__ float wred[8][8];
    const int tid = threadIdx.x;
    const int g0  = blockIdx.x * 8;

    for (int i = tid; i < 8 * FH; i += 512)
        ms[i >> 7][i & 127] = means[(size_t)g0 * FH + i];
    __syncthreads();

    const int f = tid;
    float acc[8];
    float bb = bp1[f];
#pragma unroll
    for (int gi = 0; gi < 8; ++gi) acc[gi] = bb;
    for (int k = 0; k < FH; ++k) {
        float w = Wp1[(size_t)k * FP + f];
#pragma unroll
        for (int gi = 0; gi < 8; ++gi) acc[gi] += ms[gi][k] * w;
    }
    float w2 = Wp2[f];
#pragma unroll
    for (int gi = 0; gi < 8; ++gi) {
        float v = fmaxf(acc[gi], 0.f) * w2;
#pragma unroll
        for (int o = 32; o > 0; o >>= 1) v += __shfl_down(v, o, 64);
        if ((tid & 63) == 0) wred[tid >> 6][gi] = v;
    }
    __syncthreads();
    if (tid < 8) {
        float s = 0.f;
#pragma unroll
        for (int w = 0; w < 8; ++w) s += wred[w][tid];
        out[g0 + tid] = s + bp2[0];
    }
}

extern "C" void kernel_launch(void* const* d_in, const int* in_sizes, int n_in,
                              void* d_out, int out_size, void* d_ws, size_t ws_size,
                              hipStream_t stream) {
    const float* nf   = (const float*)d_in[0];
    const int*   pair = (const int*)d_in[2];
    const int*   nn   = (const int*)d_in[3];
    const float* W0  = (const float*)d_in[5];  const float* b0  = (const float*)d_in[6];
    const float* W1  = (const float*)d_in[7];  const float* b1  = (const float*)d_in[8];
    const float* W2  = (const float*)d_in[9];  const float* b2  = (const float*)d_in[10];
    const float* Wp1 = (const float*)d_in[11]; const float* bp1 = (const float*)d_in[12];
    const float* Wp2 = (const float*)d_in[13]; const float* bp2 = (const float*)d_in[14];

    float* means = (float*)d_ws;                                   // 1,024,000 B
    u16*   WpH   = (u16*)((char*)d_ws + (1 << 20));                // 81,920 B
    u16*   WpL   = (u16*)((char*)d_ws + (1 << 20) + 80 * 1024);    // 81,920 B
    float* out   = (float*)d_out;

    hipLaunchKernelGGL(pack_w, dim3(20), dim3(256), 0, stream, W0, W1, W2, WpH, WpL);
    hipLaunchKernelGGL(gcn_fused, dim3(NG), dim3(512), 0, stream,
                       nf, pair, nn, b0, b1, b2, WpH, WpL, means);
    hipLaunchKernelGGL(mlp_head, dim3(NG / 8), dim3(512), 0, stream,
                       means, Wp1, bp1, Wp2, bp2, out);
}

// Round 10
// 86.706 us; speedup vs baseline: 4.0036x; 1.1705x over previous
//
#include <hip/hip_runtime.h>

#define NG   2000
#define NPG  50
#define EPG  800
#define F0   64
#define FH   128
#define FP   512

typedef __attribute__((ext_vector_type(8))) short  short8;
typedef __attribute__((ext_vector_type(8))) __bf16 bf16x8;
typedef __attribute__((ext_vector_type(4))) float  f32x4;
typedef unsigned short u16;
typedef unsigned int   u32;

__device__ inline u16 bf16_rne(float x) {
    u32 u = __builtin_bit_cast(u32, x);
    u += 0x7fffu + ((u >> 16) & 1u);
    return (u16)(u >> 16);
}
__device__ inline float bf16f(u16 h) {
    u32 u = ((u32)h) << 16;
    return __builtin_bit_cast(float, u);
}
// HW packed convert: dst.b16[0] = bf16(lo_src), dst.b16[1] = bf16(hi_src)
__device__ inline u32 cvtpk2(float lo, float hi) {
    u32 r;
    asm("v_cvt_pk_bf16_f32 %0, %1, %2" : "=v"(r) : "v"(lo), "v"(hi));
    return r;
}
// split (v0,v1) -> packed hi-pair and residual lo-pair
__device__ inline void split2(float v0, float v1, u32& hp, u32& lp) {
    hp = cvtpk2(v0, v1);
    float h0 = __builtin_bit_cast(float, hp << 16);
    float h1 = __builtin_bit_cast(float, hp & 0xffff0000u);
    lp = cvtpk2(v0 - h0, v1 - h1);
}
__device__ inline f32x4 mfma16(short8 a, short8 b, f32x4 c) {
    return __builtin_amdgcn_mfma_f32_16x16x32_bf16(
        __builtin_bit_cast(bf16x8, a), __builtin_bit_cast(bf16x8, b), c, 0, 0, 0);
}

// swizzled LDS index helpers (u16 units; XOR 16B-chunk id with row bits)
__device__ inline int xb_idx(int row, int col)  { return row * 128 + (col ^ ((row  & 7) << 3)); }
__device__ inline int tb_idx(int feat, int node){ return feat * 64 + (node ^ ((feat & 7) << 3)); }
__device__ inline int ab_idx(int d, int s)      { return d * 64 + (s ^ ((d  & 7) << 3)); }

// ---------- one-time W split+pack into MFMA B-fragment layout ----------
__global__ __launch_bounds__(256) void pack_w(
    const float* __restrict__ W0, const float* __restrict__ W1,
    const float* __restrict__ W2, u16* __restrict__ WpH, u16* __restrict__ WpL)
{
    int t = blockIdx.x * 256 + threadIdx.x;
    if (t >= 80 * 64) return;
    int fid = t >> 6, lane = t & 63;
    const float* W; int nsub, kstep;
    if (fid < 16)      { W = W0; int r = fid;      nsub = r >> 1; kstep = r & 1; }
    else if (fid < 48) { W = W1; int r = fid - 16; nsub = r >> 2; kstep = r & 3; }
    else               { W = W2; int r = fid - 48; nsub = r >> 2; kstep = r & 3; }
    int n  = nsub * 16 + (lane & 15);
    int kb = kstep * 32 + (lane >> 4) * 8;
    size_t off = (size_t)fid * 512 + (size_t)lane * 8;
#pragma unroll
    for (int i = 0; i < 8; ++i) {
        float v = W[(size_t)(kb + i) * FH + n];
        u16 h = bf16_rne(v);
        WpH[off + i] = h;
        WpL[off + i] = bf16_rne(v - bf16f(h));
    }
}

// ---------- MFMA1: T^T[feat][node] = ((X @ W) * nout_row)^T ----------
// wave = nsg (one 16-feat column group) -> W frags unique per wave (4x less L2).
template<int KST>
__device__ void mfma1_fn(const u16* __restrict__ WpH, const u16* __restrict__ WpL,
                         int fid0, const u16* XbH, const u16* XbL,
                         u16* TbH, u16* TbL, const float* nout64,
                         int lane, int nsg)
{
    const int l15 = lane & 15, lk = lane >> 4;
    const int feat = nsg * 16 + l15;
    short8 bh[KST], bl[KST];
#pragma unroll
    for (int ks = 0; ks < KST; ++ks) {
        size_t off = (size_t)(fid0 + nsg * KST + ks) * 512 + (size_t)lane * 8;
        bh[ks] = *(const short8*)(WpH + off);
        bl[ks] = *(const short8*)(WpL + off);
    }
#pragma unroll
    for (int ms = 0; ms < 4; ++ms) {
        const int arow = ms * 16 + l15;
        f32x4 acc = {0.f, 0.f, 0.f, 0.f};
#pragma unroll
        for (int ks = 0; ks < KST; ++ks) {
            int c0 = ks * 32 + lk * 8;
            short8 ah = *(const short8*)&XbH[xb_idx(arow, c0)];
            short8 al = *(const short8*)&XbL[xb_idx(arow, c0)];
            acc = mfma16(ah, bh[ks], acc);
            acc = mfma16(ah, bl[ks], acc);
            acc = mfma16(al, bh[ks], acc);
        }
        const int nb = ms * 16 + lk * 4;        // D rows = nodes
        float4 nq = *(const float4*)&nout64[nb];  // 0 for nodes >= NPG
        u32 h01, l01, h23, l23;
        split2(acc[0] * nq.x, acc[1] * nq.y, h01, l01);
        split2(acc[2] * nq.z, acc[3] * nq.w, h23, l23);
        int idx = tb_idx(feat, nb);
        *(uint2*)&TbH[idx] = make_uint2(h01, h23);
        *(uint2*)&TbL[idx] = make_uint2(l01, l23);
    }
}

// ---------- MFMA2: X' = relu((C @ T) * nin_row + b) ; C = exact int counts ----------
template<bool LAST>
__device__ void mfma2_fn(const float* __restrict__ bias, const u16* AhB,
                         const u16* TbH, const u16* TbL,
                         u16* XbH, u16* XbL, float* pool, const float* nin64,
                         int lane, int mstrip, int nhalf)
{
    const int l15 = lane & 15, lk = lane >> 4;
    const int arow = mstrip * 16 + l15;
    short8 a0 = *(const short8*)&AhB[ab_idx(arow, lk * 8)];        // rows>=50 are zero
    short8 a1 = *(const short8*)&AhB[ab_idx(arow, 32 + lk * 8)];
    const int nb = mstrip * 16 + lk * 4;
    float4 ninq = *(const float4*)&nin64[nb];
#pragma unroll
    for (int ns = 0; ns < 4; ++ns) {
        const int nsg  = nhalf * 4 + ns;
        const int feat = nsg * 16 + l15;
        const float bc = bias[feat];
        f32x4 acc = {0.f, 0.f, 0.f, 0.f};
        short8 bh0 = *(const short8*)&TbH[tb_idx(feat, lk * 8)];
        short8 bl0 = *(const short8*)&TbL[tb_idx(feat, lk * 8)];
        short8 bh1 = *(const short8*)&TbH[tb_idx(feat, 32 + lk * 8)];
        short8 bl1 = *(const short8*)&TbL[tb_idx(feat, 32 + lk * 8)];
        acc = mfma16(a0, bh0, acc);
        acc = mfma16(a0, bl0, acc);
        acc = mfma16(a1, bh1, acc);
        acc = mfma16(a1, bl1, acc);
        float v0 = (nb + 0 < NPG) ? fmaxf(fmaf(acc[0], ninq.x, bc), 0.f) : 0.f;
        float v1 = (nb + 1 < NPG) ? fmaxf(fmaf(acc[1], ninq.y, bc), 0.f) : 0.f;
        float v2 = (nb + 2 < NPG) ? fmaxf(fmaf(acc[2], ninq.z, bc), 0.f) : 0.f;
        float v3 = (nb + 3 < NPG) ? fmaxf(fmaf(acc[3], ninq.w, bc), 0.f) : 0.f;
        if (LAST) {
            float vs = v0 + v1 + v2 + v3;
            vs += __shfl_xor(vs, 16, 64);
            vs += __shfl_xor(vs, 32, 64);
            if (lane < 16) atomicAdd(&pool[nsg * 16 + lane], vs);
        } else {
            u32 hp01, lp01, hp23, lp23;
            split2(v0, v1, hp01, lp01);
            split2(v2, v3, hp23, lp23);
            XbH[xb_idx(nb + 0, feat)] = (u16)hp01;
            XbH[xb_idx(nb + 1, feat)] = (u16)(hp01 >> 16);
            XbH[xb_idx(nb + 2, feat)] = (u16)hp23;
            XbH[xb_idx(nb + 3, feat)] = (u16)(hp23 >> 16);
            XbL[xb_idx(nb + 0, feat)] = (u16)lp01;
            XbL[xb_idx(nb + 1, feat)] = (u16)(lp01 >> 16);
            XbL[xb_idx(nb + 2, feat)] = (u16)lp23;
            XbL[xb_idx(nb + 3, feat)] = (u16)(lp23 >> 16);
        }
    }
}

// ---------- main fused kernel: one block = one graph ----------
__global__ __launch_bounds__(512, 4) void gcn_fused(
    const float* __restrict__ nf, const int* __restrict__ pair,
    const int* __restrict__ num_nodes,
    const float* __restrict__ b0, const float* __restrict__ b1,
    const float* __restrict__ b2,
    const u16* __restrict__ WpH, const u16* __restrict__ WpL,
    float* __restrict__ means)
{
    __shared__ u16 XbH[64 * 128], XbL[64 * 128];   // X hi/lo [node][feat], swizzled
    __shared__ u16 TbH[128 * 64], TbL[128 * 64];   // T^T hi/lo [feat][node], swizzled
    __shared__ u16 AhB[64 * 64];                   // adjacency counts, bf16 (exact)
    __shared__ float pool[FH];
    __shared__ int   din[NPG], dout[NPG];
    __shared__ float nin64[64], nout64[64];

    float* cnt = (float*)TbH;   // f32 count scratch aliased over TbH (dead until L0 mfma1)

    const int tid  = threadIdx.x;
    const int g    = blockIdx.x;
    const int base = g * NPG, ebase = g * EPG;
    const int* srcp = pair;
    const int* dstp = pair + (size_t)NG * EPG;

    // ---- init ----
    if (tid < NPG) { din[tid] = 0; dout[tid] = 0; }
    if (tid < FH) pool[tid] = 0.f;
    for (int i = tid; i < 4096; i += 512) cnt[i] = 0.f;
    for (int i = 3200 + tid; i < 4096; i += 512) {   // Xb pad rows 50-63
        ((u32*)XbH)[i] = 0u; ((u32*)XbL)[i] = 0u;
    }
    __syncthreads();

    // ---- single edge pass: degrees + dense count matrix (exact ints in f32) ----
    for (int e = tid; e < EPG; e += 512) {
        int s = srcp[ebase + e] - base, d = dstp[ebase + e] - base;
        atomicAdd(&dout[s], 1);
        atomicAdd(&din [d], 1);
        atomicAdd(&cnt[ab_idx(d, s)], 1.0f);
    }
    // ---- X0 load + hi/lo split (raw features; norms folded into T / epilogue) ----
    for (int i = tid; i < NPG * 16; i += 512) {
        int n = i >> 4, c4 = (i & 15) * 4;
        float4 v = *(const float4*)(nf + (size_t)(base + n) * F0 + c4);
        u32 h01, l01, h23, l23;
        split2(v.x, v.y, h01, l01);
        split2(v.z, v.w, h23, l23);
        int idx = xb_idx(n, c4);
        *(uint2*)&XbH[idx] = make_uint2(h01, h23);
        *(uint2*)&XbL[idx] = make_uint2(l01, l23);
    }
    __syncthreads();

    // ---- norms (zero-padded to 64) + counts -> exact bf16 ----
    if (tid < 64) {
        nout64[tid] = (tid < NPG) ? rsqrtf((float)max(dout[tid], 1)) : 0.f;
        nin64 [tid] = (tid < NPG) ? rsqrtf((float)max(din [tid], 1)) : 0.f;
    }
    for (int i = tid; i < 2048; i += 512)
        ((u32*)AhB)[i] = cvtpk2(cnt[2 * i], cnt[2 * i + 1]);
    __syncthreads();

    const int lane   = tid & 63;
    const int wv     = __builtin_amdgcn_readfirstlane(tid >> 6);
    const int mstrip = wv & 3, nhalf = wv >> 2;

    mfma1_fn<2>(WpH, WpL, 0,  XbH, XbL, TbH, TbL, nout64, lane, wv);
    __syncthreads();
    mfma2_fn<false>(b0, AhB, TbH, TbL, XbH, XbL, pool, nin64, lane, mstrip, nhalf);
    __syncthreads();
    mfma1_fn<4>(WpH, WpL, 16, XbH, XbL, TbH, TbL, nout64, lane, wv);
    __syncthreads();
    mfma2_fn<false>(b1, AhB, TbH, TbL, XbH, XbL, pool, nin64, lane, mstrip, nhalf);
    __syncthreads();
    mfma1_fn<4>(WpH, WpL, 48, XbH, XbL, TbH, TbL, nout64, lane, wv);
    __syncthreads();
    mfma2_fn<true>(b2, AhB, TbH, TbL, XbH, XbL, pool, nin64, lane, mstrip, nhalf);
    __syncthreads();

    if (tid < FH) means[(size_t)g * FH + tid] = pool[tid] / (float)num_nodes[g];
}

// ---------------- Kernel 3: MLP head ----------------
__global__ __launch_bounds__(512) void mlp_head(
    const float* __restrict__ means, const float* __restrict__ Wp1,
    const float* __restrict__ bp1,   const float* __restrict__ Wp2,
    const float* __restrict__ bp2,   float* __restrict__ out)
{
    __shared__ float ms[8][FH];
    __shared__ float wred[8][8];
    const int tid = threadIdx.x;
    const int g0  = blockIdx.x * 8;

    for (int i = tid; i < 8 * FH; i += 512)
        ms[i >> 7][i & 127] = means[(size_t)g0 * FH + i];
    __syncthreads();

    const int f = tid;
    float acc[8];
    float bb = bp1[f];
#pragma unroll
    for (int gi = 0; gi < 8; ++gi) acc[gi] = bb;
    for (int k = 0; k < FH; ++k) {
        float w = Wp1[(size_t)k * FP + f];
#pragma unroll
        for (int gi = 0; gi < 8; ++gi) acc[gi] += ms[gi][k] * w;
    }
    float w2 = Wp2[f];
#pragma unroll
    for (int gi = 0; gi < 8; ++gi) {
        float v = fmaxf(acc[gi], 0.f) * w2;
#pragma unroll
        for (int o = 32; o > 0; o >>= 1) v += __shfl_down(v, o, 64);
        if ((tid & 63) == 0) wred[tid >> 6][gi] = v;
    }
    __syncthreads();
    if (tid < 8) {
        float s = 0.f;
#pragma unroll
        for (int w = 0; w < 8; ++w) s += wred[w][tid];
        out[g0 + tid] = s + bp2[0];
    }
}

extern "C" void kernel_launch(void* const* d_in, const int* in_sizes, int n_in,
                              void* d_out, int out_size, void* d_ws, size_t ws_size,
                              hipStream_t stream) {
    const float* nf   = (const float*)d_in[0];
    const int*   pair = (const int*)d_in[2];
    const int*   nn   = (const int*)d_in[3];
    const float* W0  = (const float*)d_in[5];  const float* b0  = (const float*)d_in[6];
    const float* W1  = (const float*)d_in[7];  const float* b1  = (const float*)d_in[8];
    const float* W2  = (const float*)d_in[9];  const float* b2  = (const float*)d_in[10];
    const float* Wp1 = (const float*)d_in[11]; const float* bp1 = (const float*)d_in[12];
    const float* Wp2 = (const float*)d_in[13]; const float* bp2 = (const float*)d_in[14];

    float* means = (float*)d_ws;                                   // 1,024,000 B
    u16*   WpH   = (u16*)((char*)d_ws + (1 << 20));                // 81,920 B
    u16*   WpL   = (u16*)((char*)d_ws + (1 << 20) + 80 * 1024);    // 81,920 B
    float* out   = (float*)d_out;

    hipLaunchKernelGGL(pack_w, dim3(20), dim3(256), 0, stream, W0, W1, W2, WpH, WpL);
    hipLaunchKernelGGL(gcn_fused, dim3(NG), dim3(512), 0, stream,
                       nf, pair, nn, b0, b1, b2, WpH, WpL, means);
    hipLaunchKernelGGL(mlp_head, dim3(NG / 8), dim3(512), 0, stream,
                       means, Wp1, bp1, Wp2, bp2, out);
}